// Round 13
// baseline (551.987 us; speedup 1.0000x reference)
//
#include <hip/hip_runtime.h>

// ---------------- problem constants ----------------
constexpr int cN     = 20000;
constexpr int cT     = 8;
constexpr int cFIN   = 64;
constexpr int cHEADS = 4;
constexpr int cF     = 32;
constexpr int cHID   = 128;        // cHEADS * cF
constexpr int cE     = 320000;
constexpr int cET    = cE + cN;    // edges + self loops
constexpr int cR     = cN * cT;    // 160000 batched rows, rho = t*N + n (t-major)
constexpr float cLEAKY = 0.2f;

typedef __attribute__((ext_vector_type(8))) short bf16x8;   // MFMA A/B frag
typedef __attribute__((ext_vector_type(4))) float f32x4;    // MFMA C/D frag

static __device__ __forceinline__ unsigned short f2bfu(float f) {
    unsigned int u;
    __builtin_memcpy(&u, &f, 4);
    u += 0x7FFFu + ((u >> 16) & 1u);
    return (unsigned short)(u >> 16);
}
static __device__ __forceinline__ void unpack2(unsigned int v, float& lo, float& hi) {
    unsigned int ul = v << 16, uh = v & 0xFFFF0000u;
    __builtin_memcpy(&lo, &ul, 4);
    __builtin_memcpy(&hi, &uh, 4);
}
static __device__ __forceinline__ unsigned int pack2(float lo, float hi) {
    unsigned int ul, uh;
    __builtin_memcpy(&ul, &lo, 4);
    __builtin_memcpy(&uh, &hi, 4);
    ul += 0x7FFFu + ((ul >> 16) & 1u);
    uh += 0x7FFFu + ((uh >> 16) & 1u);
    return (ul >> 16) | (uh & 0xFFFF0000u);
}

// ---------------- conversions ----------------
// x [N,T,64] fp32 -> xb [rho=(t,n)][64] bf16 (t-major transpose)
__global__ void cvt_x_kernel(const float* x, unsigned short* xb) {
    int id = blockIdx.x * 256 + threadIdx.x;   // n*64 + k
    int t  = blockIdx.y;
    int n  = id >> 6, k = id & 63;
    xb[(size_t)t * cN * cFIN + id] = f2bfu(x[(size_t)n * (cT * cFIN) + t * cFIN + k]);
}
__global__ void cvt_w_kernel(const float* W1, const float* W2, const float* lw1,
                             unsigned short* W1b, unsigned short* W2b, unsigned short* lw1b) {
    int i = blockIdx.x * 256 + threadIdx.x;
    if (i < cHID * cFIN)                      W1b[i] = f2bfu(W1[i]);
    else if (i < cHID * cFIN + cHID * cHID)   W2b[i - cHID * cFIN] = f2bfu(W2[i - cHID * cFIN]);
    else if (i < cHID * cFIN + cHID * cHID + cF * cHID)
        lw1b[i - cHID * cFIN - cHID * cHID] = f2bfu(lw1[i - cHID * cFIN - cHID * cHID]);
}

// ---------------- CSR build + degree-sort permutation ----------------
__global__ void deg_init_kernel(int* deg, int* hist) {
    int n = blockIdx.x * blockDim.x + threadIdx.x;
    if (n < cN) deg[n] = 1;   // self loop
    if (n < 128) hist[n] = 0;
}
__global__ void deg_count_kernel(const int* ei, int* deg) {
    int e = blockIdx.x * blockDim.x + threadIdx.x;
    if (e < cE) atomicAdd(&deg[ei[cE + e]], 1);
}
__global__ void scan_kernel(const int* deg, int* offs, int* cur) {
    __shared__ int lds[256];
    const int CH = 80;
    int tid  = threadIdx.x;
    int base = tid * CH;
    int tot = 0;
    for (int j = 0; j < CH; j++) {
        int idx = base + j;
        if (idx < cN) tot += deg[idx];
    }
    lds[tid] = tot;
    __syncthreads();
    for (int off = 1; off < 256; off <<= 1) {
        int v = (tid >= off) ? lds[tid - off] : 0;
        __syncthreads();
        lds[tid] += v;
        __syncthreads();
    }
    int run = lds[tid] - tot;
    for (int j = 0; j < CH; j++) {
        int idx = base + j;
        if (idx < cN) { offs[idx] = run; cur[idx] = run; run += deg[idx]; }
    }
    if (tid == 255) offs[cN] = lds[255];
}
__global__ void scatter_kernel(const int* ei, int* cur, int* csr) {
    int e = blockIdx.x * blockDim.x + threadIdx.x;
    if (e >= cET) return;
    int s, d;
    if (e < cE) { s = ei[e]; d = ei[cE + e]; }
    else        { s = e - cE; d = s; }
    int pos = atomicAdd(&cur[d], 1);
    csr[pos] = s;
}
__global__ void hist_kernel(const int* deg, int* hist) {
    int n = blockIdx.x * blockDim.x + threadIdx.x;
    if (n < cN) atomicAdd(&hist[min(deg[n], 127)], 1);
}
__global__ void hist_scan_kernel(const int* hist, int* hcur) {
    __shared__ int tmp[128];
    int tid = threadIdx.x;     // 128 threads
    int v0 = hist[tid];
    tmp[tid] = v0;
    __syncthreads();
    for (int off = 1; off < 128; off <<= 1) {
        int v = (tid >= off) ? tmp[tid - off] : 0;
        __syncthreads();
        tmp[tid] += v;
        __syncthreads();
    }
    hcur[tid] = tmp[tid] - v0;   // exclusive prefix
}
__global__ void perm_scatter_kernel(const int* deg, int* hcur, int* perm) {
    int n = blockIdx.x * blockDim.x + threadIdx.x;
    if (n >= cN) return;
    int b = min(deg[n], 127);
    int pos = atomicAdd(&hcur[b], 1);
    perm[pos] = n;
}

// ---------------- batched MFMA GEMM + fused scores (rows = rho, t-major) ----------------
template<int K>
__global__ __launch_bounds__(256) void gemm_mfma_kernel(
        const unsigned short* __restrict__ A, const unsigned short* __restrict__ W,
        const float* __restrict__ a_src, const float* __restrict__ a_dst,
        unsigned short* __restrict__ hb, float* __restrict__ es, float* __restrict__ ed) {
    __shared__ float hl[64][132];      // 33.8 KB
    int tid  = threadIdx.x;
    int wave = tid >> 6;
    int lane = tid & 63;
    int q    = lane >> 4;
    int mi   = lane & 15;
    int m0   = blockIdx.x * 64 + wave * 16;   // R % 64 == 0: no tail

    bf16x8 afrag[K / 32];
    #pragma unroll
    for (int s = 0; s < K / 32; s++)
        afrag[s] = *(const bf16x8*)(A + (size_t)(m0 + mi) * K + s * 32 + q * 8);

    f32x4 acc[8];
    #pragma unroll
    for (int ct = 0; ct < 8; ct++) acc[ct] = (f32x4){0.f, 0.f, 0.f, 0.f};
    #pragma unroll
    for (int ct = 0; ct < 8; ct++) {
        int c = ct * 16 + mi;
        #pragma unroll
        for (int s = 0; s < K / 32; s++) {
            bf16x8 bfrag = *(const bf16x8*)(W + (size_t)c * K + s * 32 + q * 8);
            acc[ct] = __builtin_amdgcn_mfma_f32_16x16x32_bf16(afrag[s], bfrag, acc[ct], 0, 0, 0);
        }
    }

    #pragma unroll
    for (int ct = 0; ct < 8; ct++)
        #pragma unroll
        for (int r = 0; r < 4; r++)
            hl[wave * 16 + q * 4 + r][ct * 16 + mi] = acc[ct][r];
    __syncthreads();

    // scores: wave hd handles head hd for all 64 rows
    {
        int r2 = tid & 63;
        int hd = tid >> 6;
        int rg = blockIdx.x * 64 + r2;
        const float* hr = &hl[r2][hd * cF];
        const float* sa = a_src + hd * cF;
        const float* da = a_dst + hd * cF;
        float s1 = 0.f, s2 = 0.f;
        #pragma unroll 8
        for (int f = 0; f < cF; f++) {
            float hv = hr[f];
            s1 += hv * sa[f];
            s2 += hv * da[f];
        }
        es[rg * cHEADS + hd] = s1;
        ed[rg * cHEADS + hd] = s2;
    }

    // coalesced bf16 writeout
    size_t base = (size_t)blockIdx.x * 64 * cHID;
    #pragma unroll
    for (int it = 0; it < 8; it++) {
        int g   = tid + it * 256;
        int row = g >> 5;
        int c4  = (g & 31) * 4;
        float4 v = *(const float4*)&hl[row][c4];
        unsigned int p0 = pack2(v.x, v.y), p1 = pack2(v.z, v.w);
        *(uint2*)(hb + base + (size_t)row * cHID + c4) = make_uint2(p0, p1);
    }
}

// ---------------- t-plane agg: degree-sorted rows + XCD-affine plane swizzle ----------------
// 1D grid of (cN/16)*cT blocks: t = b & 7 (same t -> same XCD under round-robin),
// node from degree-sorted perm (wave rows have ~equal degree: no divergence).
// 16 lanes per row, 16B (8 bf16) per lane.
__global__ void agg_kernel(const unsigned short* __restrict__ hb, const float* __restrict__ es,
                           const float* __restrict__ ed,
                           const int* __restrict__ offs, const int* __restrict__ csr,
                           const int* __restrict__ perm,
                           const float* __restrict__ bias, unsigned short* __restrict__ outb) {
    int b    = blockIdx.x;
    int t    = b & 7;
    int g    = b >> 3;
    int lrow = threadIdx.x >> 4;
    int n    = perm[g * 16 + lrow];
    int j    = threadIdx.x & 15;        // features 8j..8j+7
    int head = j >> 2;
    size_t plane = (size_t)t * cN;
    int rho = t * cN + n;
    int s0 = offs[n], s1 = offs[n + 1];
    float edn = ed[(size_t)rho * cHEADS + head];
    const unsigned short* hp = hb + plane * cHID;
    const float* ep = es + plane * cHEADS;

    float acc[8] = {};
    float den = 0.f;
    int i = s0;
    for (; i + 1 < s1; i += 2) {
        int sa = csr[i], sb = csr[i + 1];
        uint4 ra = *(const uint4*)(hp + (size_t)sa * cHID + 8 * j);
        uint4 rb = *(const uint4*)(hp + (size_t)sb * cHID + 8 * j);
        float ea = ep[sa * cHEADS + head] + edn;
        float eb = ep[sb * cHEADS + head] + edn;
        ea = (ea >= 0.f) ? ea : cLEAKY * ea;
        eb = (eb >= 0.f) ? eb : cLEAKY * eb;
        float wa = __expf(ea), wb = __expf(eb);
        den += wa + wb;
        float l0, h0, l1, h1;
        unpack2(ra.x, l0, h0); acc[0] += wa * l0; acc[1] += wa * h0;
        unpack2(ra.y, l1, h1); acc[2] += wa * l1; acc[3] += wa * h1;
        unpack2(ra.z, l0, h0); acc[4] += wa * l0; acc[5] += wa * h0;
        unpack2(ra.w, l1, h1); acc[6] += wa * l1; acc[7] += wa * h1;
        unpack2(rb.x, l0, h0); acc[0] += wb * l0; acc[1] += wb * h0;
        unpack2(rb.y, l1, h1); acc[2] += wb * l1; acc[3] += wb * h1;
        unpack2(rb.z, l0, h0); acc[4] += wb * l0; acc[5] += wb * h0;
        unpack2(rb.w, l1, h1); acc[6] += wb * l1; acc[7] += wb * h1;
    }
    if (i < s1) {
        int sa = csr[i];
        uint4 ra = *(const uint4*)(hp + (size_t)sa * cHID + 8 * j);
        float ea = ep[sa * cHEADS + head] + edn;
        ea = (ea >= 0.f) ? ea : cLEAKY * ea;
        float wa = __expf(ea);
        den += wa;
        float l0, h0;
        unpack2(ra.x, l0, h0); acc[0] += wa * l0; acc[1] += wa * h0;
        unpack2(ra.y, l0, h0); acc[2] += wa * l0; acc[3] += wa * h0;
        unpack2(ra.z, l0, h0); acc[4] += wa * l0; acc[5] += wa * h0;
        unpack2(ra.w, l0, h0); acc[6] += wa * l0; acc[7] += wa * h0;
    }
    float inv = 1.f / (den + 1e-16f);
    float4 b0 = *(const float4*)(bias + 8 * j);
    float4 b1 = *(const float4*)(bias + 8 * j + 4);
    float r0 = acc[0] * inv + b0.x; r0 = (r0 > 0.f) ? r0 : expm1f(r0);
    float r1 = acc[1] * inv + b0.y; r1 = (r1 > 0.f) ? r1 : expm1f(r1);
    float r2 = acc[2] * inv + b0.z; r2 = (r2 > 0.f) ? r2 : expm1f(r2);
    float r3 = acc[3] * inv + b0.w; r3 = (r3 > 0.f) ? r3 : expm1f(r3);
    float r4 = acc[4] * inv + b1.x; r4 = (r4 > 0.f) ? r4 : expm1f(r4);
    float r5 = acc[5] * inv + b1.y; r5 = (r5 > 0.f) ? r5 : expm1f(r5);
    float r6 = acc[6] * inv + b1.z; r6 = (r6 > 0.f) ? r6 : expm1f(r6);
    float r7 = acc[7] * inv + b1.w; r7 = (r7 > 0.f) ? r7 : expm1f(r7);
    uint4 o;
    o.x = pack2(r0, r1); o.y = pack2(r2, r3); o.z = pack2(r4, r5); o.w = pack2(r6, r7);
    *(uint4*)(outb + (size_t)rho * cHID + 8 * j) = o;
}

// ---------------- MFMA MLP head: relu(X@lw1.T+lb1)@lw2.T + lb2 -> out[rho] ----------------
__global__ __launch_bounds__(256) void TemporalGAT_20005957665499_kernel(
        const unsigned short* __restrict__ X, const unsigned short* __restrict__ lw1b,
        const float* __restrict__ lb1, const float* __restrict__ lw2,
        const float* __restrict__ lb2, float* __restrict__ out) {
    int tid  = threadIdx.x;
    int wave = tid >> 6;
    int lane = tid & 63;
    int q    = lane >> 4;
    int mi   = lane & 15;
    int m0   = blockIdx.x * 64 + wave * 16;

    bf16x8 afrag[4];
    #pragma unroll
    for (int s = 0; s < 4; s++)
        afrag[s] = *(const bf16x8*)(X + (size_t)(m0 + mi) * cHID + s * 32 + q * 8);

    f32x4 acc[2];
    acc[0] = (f32x4){0.f, 0.f, 0.f, 0.f};
    acc[1] = (f32x4){0.f, 0.f, 0.f, 0.f};
    #pragma unroll
    for (int ct = 0; ct < 2; ct++) {
        int c = ct * 16 + mi;
        #pragma unroll
        for (int s = 0; s < 4; s++) {
            bf16x8 bfrag = *(const bf16x8*)(lw1b + (size_t)c * cHID + s * 32 + q * 8);
            acc[ct] = __builtin_amdgcn_mfma_f32_16x16x32_bf16(afrag[s], bfrag, acc[ct], 0, 0, 0);
        }
    }

    float lb1a = lb1[mi], lb1b_ = lb1[16 + mi];
    float lw2a = lw2[mi], lw2b_ = lw2[16 + mi];
    float l2 = lb2[0];
    #pragma unroll
    for (int r = 0; r < 4; r++) {
        float va = acc[0][r] + lb1a; va = fmaxf(va, 0.f);
        float vb = acc[1][r] + lb1b_; vb = fmaxf(vb, 0.f);
        float v = va * lw2a + vb * lw2b_;
        v += __shfl_xor(v, 1);
        v += __shfl_xor(v, 2);
        v += __shfl_xor(v, 4);
        v += __shfl_xor(v, 8);
        if (mi == 0) out[m0 + q * 4 + r] = v + l2;   // rho-major == [T,N] output layout
    }
}

// ---------------- launch ----------------
extern "C" void kernel_launch(void* const* d_in, const int* in_sizes, int n_in,
                              void* d_out, int out_size, void* d_ws, size_t ws_size,
                              hipStream_t stream) {
    const float* x   = (const float*)d_in[0];   // [N,T,64] fp32
    const int*   ei  = (const int*)d_in[1];
    const float* W1  = (const float*)d_in[2];
    const float* as1 = (const float*)d_in[3];
    const float* ad1 = (const float*)d_in[4];
    const float* b1  = (const float*)d_in[5];
    const float* W2  = (const float*)d_in[6];
    const float* as2 = (const float*)d_in[7];
    const float* ad2 = (const float*)d_in[8];
    const float* b2  = (const float*)d_in[9];
    const float* lw1 = (const float*)d_in[10];
    const float* lb1 = (const float*)d_in[11];
    const float* lw2 = (const float*)d_in[12];
    const float* lb2 = (const float*)d_in[13];
    float* out = (float*)d_out;                 // [T,N,1] fp32 == rho-major
    (void)in_sizes; (void)n_in; (void)out_size; (void)ws_size;

    // workspace carve (~150 MB of 256 MB), 256B-aligned
    char* ws = (char*)d_ws;
    size_t o = 0;
    auto carveN = [&](size_t bytes) { void* p = ws + o; o += (bytes + 255) & ~(size_t)255; return p; };
    unsigned short* xb   = (unsigned short*)carveN((size_t)cR * cFIN * 2);    // 20.5 MB
    unsigned short* hb   = (unsigned short*)carveN((size_t)cR * cHID * 2);    // 41 MB
    unsigned short* xb2  = (unsigned short*)carveN((size_t)cR * cHID * 2);    // 41 MB
    unsigned short* xb3  = (unsigned short*)carveN((size_t)cR * cHID * 2);    // 41 MB
    unsigned short* W1b  = (unsigned short*)carveN((size_t)cHID * cFIN * 2);
    unsigned short* W2b  = (unsigned short*)carveN((size_t)cHID * cHID * 2);
    unsigned short* lw1b = (unsigned short*)carveN((size_t)cF * cHID * 2);
    float* es_buf  = (float*)carveN((size_t)cR * cHEADS * 4);                 // 2.6 MB
    float* ed_buf  = (float*)carveN((size_t)cR * cHEADS * 4);
    int*   deg     = (int*)carveN((size_t)cN * 4);
    int*   offs    = (int*)carveN((size_t)(cN + 1) * 4);
    int*   cursor  = (int*)carveN((size_t)cN * 4);
    int*   csr     = (int*)carveN((size_t)cET * 4);
    int*   hist    = (int*)carveN(128 * 4);
    int*   hcur    = (int*)carveN(128 * 4);
    int*   perm    = (int*)carveN((size_t)cN * 4);

    // ---- conversions ----
    cvt_x_kernel<<<dim3(cN * cFIN / 256, cT), 256, 0, stream>>>(x, xb);
    cvt_w_kernel<<<(cHID * cFIN + cHID * cHID + cF * cHID + 255) / 256, 256, 0, stream>>>(
        W1, W2, lw1, W1b, W2b, lw1b);

    // ---- CSR build + degree-sort perm ----
    deg_init_kernel<<<(cN + 255) / 256, 256, 0, stream>>>(deg, hist);
    deg_count_kernel<<<(cE + 255) / 256, 256, 0, stream>>>(ei, deg);
    scan_kernel<<<1, 256, 0, stream>>>(deg, offs, cursor);
    scatter_kernel<<<(cET + 255) / 256, 256, 0, stream>>>(ei, cursor, csr);
    hist_kernel<<<(cN + 255) / 256, 256, 0, stream>>>(deg, hist);
    hist_scan_kernel<<<1, 128, 0, stream>>>(hist, hcur);
    perm_scatter_kernel<<<(cN + 255) / 256, 256, 0, stream>>>(deg, hcur, perm);

    // ---- layer 1 ----
    gemm_mfma_kernel<cFIN><<<cR / 64, 256, 0, stream>>>(xb, W1b, as1, ad1, hb, es_buf, ed_buf);
    agg_kernel<<<(cN / 16) * cT, 256, 0, stream>>>(hb, es_buf, ed_buf, offs, csr, perm, b1, xb2);
    // ---- layer 2 ----
    gemm_mfma_kernel<cHID><<<cR / 64, 256, 0, stream>>>(xb2, W2b, as2, ad2, hb, es_buf, ed_buf);
    agg_kernel<<<(cN / 16) * cT, 256, 0, stream>>>(hb, es_buf, ed_buf, offs, csr, perm, b2, xb3);
    // ---- MFMA MLP head -> out ----
    TemporalGAT_20005957665499_kernel<<<cR / 64, 256, 0, stream>>>(xb3, lw1b, lb1, lw2, lb2, out);
}

// Round 14
// 444.412 us; speedup vs baseline: 1.2421x; 1.2421x over previous
//
#include <hip/hip_runtime.h>

// ---------------- problem constants ----------------
constexpr int cN     = 20000;
constexpr int cT     = 8;
constexpr int cFIN   = 64;
constexpr int cHEADS = 4;
constexpr int cF     = 32;
constexpr int cHID   = 128;        // cHEADS * cF
constexpr int cE     = 320000;
constexpr int cET    = cE + cN;    // edges + self loops
constexpr int cR     = cN * cT;    // 160000 batched rows, rho = t*N + n (t-major)
constexpr float cLEAKY = 0.2f;

typedef __attribute__((ext_vector_type(8))) short bf16x8;   // MFMA A/B frag
typedef __attribute__((ext_vector_type(4))) float f32x4;    // MFMA C/D frag

static __device__ __forceinline__ unsigned short f2bfu(float f) {
    unsigned int u;
    __builtin_memcpy(&u, &f, 4);
    u += 0x7FFFu + ((u >> 16) & 1u);
    return (unsigned short)(u >> 16);
}
static __device__ __forceinline__ void unpack2(unsigned int v, float& lo, float& hi) {
    unsigned int ul = v << 16, uh = v & 0xFFFF0000u;
    __builtin_memcpy(&lo, &ul, 4);
    __builtin_memcpy(&hi, &uh, 4);
}
static __device__ __forceinline__ unsigned int pack2(float lo, float hi) {
    unsigned int ul, uh;
    __builtin_memcpy(&ul, &lo, 4);
    __builtin_memcpy(&uh, &hi, 4);
    ul += 0x7FFFu + ((ul >> 16) & 1u);
    uh += 0x7FFFu + ((uh >> 16) & 1u);
    return (ul >> 16) | (uh & 0xFFFF0000u);
}

// ---------------- conversions ----------------
// x [N,T,64] fp32 -> xb [rho=(t,n)][64] bf16 (t-major transpose)
__global__ void cvt_x_kernel(const float* x, unsigned short* xb) {
    int id = blockIdx.x * 256 + threadIdx.x;   // n*64 + k
    int t  = blockIdx.y;
    int n  = id >> 6, k = id & 63;
    xb[(size_t)t * cN * cFIN + id] = f2bfu(x[(size_t)n * (cT * cFIN) + t * cFIN + k]);
}
__global__ void cvt_w_kernel(const float* W1, const float* W2, const float* lw1,
                             unsigned short* W1b, unsigned short* W2b, unsigned short* lw1b) {
    int i = blockIdx.x * 256 + threadIdx.x;
    if (i < cHID * cFIN)                      W1b[i] = f2bfu(W1[i]);
    else if (i < cHID * cFIN + cHID * cHID)   W2b[i - cHID * cFIN] = f2bfu(W2[i - cHID * cFIN]);
    else if (i < cHID * cFIN + cHID * cHID + cF * cHID)
        lw1b[i - cHID * cFIN - cHID * cHID] = f2bfu(lw1[i - cHID * cFIN - cHID * cHID]);
}

// ---------------- CSR build ----------------
__global__ void deg_init_kernel(int* deg) {
    int n = blockIdx.x * blockDim.x + threadIdx.x;
    if (n < cN) deg[n] = 1;   // self loop
}
__global__ void deg_count_kernel(const int* ei, int* deg) {
    int e = blockIdx.x * blockDim.x + threadIdx.x;
    if (e < cE) atomicAdd(&deg[ei[cE + e]], 1);
}
__global__ void scan_kernel(const int* deg, int* offs, int* cur) {
    __shared__ int lds[256];
    const int CH = 80;
    int tid  = threadIdx.x;
    int base = tid * CH;
    int tot = 0;
    for (int j = 0; j < CH; j++) {
        int idx = base + j;
        if (idx < cN) tot += deg[idx];
    }
    lds[tid] = tot;
    __syncthreads();
    for (int off = 1; off < 256; off <<= 1) {
        int v = (tid >= off) ? lds[tid - off] : 0;
        __syncthreads();
        lds[tid] += v;
        __syncthreads();
    }
    int run = lds[tid] - tot;
    for (int j = 0; j < CH; j++) {
        int idx = base + j;
        if (idx < cN) { offs[idx] = run; cur[idx] = run; run += deg[idx]; }
    }
    if (tid == 255) offs[cN] = lds[255];
}
__global__ void scatter_kernel(const int* ei, int* cur, int* csr) {
    int e = blockIdx.x * blockDim.x + threadIdx.x;
    if (e >= cET) return;
    int s, d;
    if (e < cE) { s = ei[e]; d = ei[cE + e]; }
    else        { s = e - cE; d = s; }
    int pos = atomicAdd(&cur[d], 1);
    csr[pos] = s;
}

// ---------------- batched MFMA GEMM + fused scores (rows = rho, t-major) ----------------
template<int K>
__global__ __launch_bounds__(256) void gemm_mfma_kernel(
        const unsigned short* __restrict__ A, const unsigned short* __restrict__ W,
        const float* __restrict__ a_src, const float* __restrict__ a_dst,
        unsigned short* __restrict__ hb, float* __restrict__ es, float* __restrict__ ed) {
    __shared__ float hl[64][132];      // 33.8 KB
    int tid  = threadIdx.x;
    int wave = tid >> 6;
    int lane = tid & 63;
    int q    = lane >> 4;
    int mi   = lane & 15;
    int m0   = blockIdx.x * 64 + wave * 16;   // R % 64 == 0: no tail

    bf16x8 afrag[K / 32];
    #pragma unroll
    for (int s = 0; s < K / 32; s++)
        afrag[s] = *(const bf16x8*)(A + (size_t)(m0 + mi) * K + s * 32 + q * 8);

    f32x4 acc[8];
    #pragma unroll
    for (int ct = 0; ct < 8; ct++) acc[ct] = (f32x4){0.f, 0.f, 0.f, 0.f};
    #pragma unroll
    for (int ct = 0; ct < 8; ct++) {
        int c = ct * 16 + mi;
        #pragma unroll
        for (int s = 0; s < K / 32; s++) {
            bf16x8 bfrag = *(const bf16x8*)(W + (size_t)c * K + s * 32 + q * 8);
            acc[ct] = __builtin_amdgcn_mfma_f32_16x16x32_bf16(afrag[s], bfrag, acc[ct], 0, 0, 0);
        }
    }

    #pragma unroll
    for (int ct = 0; ct < 8; ct++)
        #pragma unroll
        for (int r = 0; r < 4; r++)
            hl[wave * 16 + q * 4 + r][ct * 16 + mi] = acc[ct][r];
    __syncthreads();

    // scores: wave hd handles head hd for all 64 rows
    {
        int r2 = tid & 63;
        int hd = tid >> 6;
        int rg = blockIdx.x * 64 + r2;
        const float* hr = &hl[r2][hd * cF];
        const float* sa = a_src + hd * cF;
        const float* da = a_dst + hd * cF;
        float s1 = 0.f, s2 = 0.f;
        #pragma unroll 8
        for (int f = 0; f < cF; f++) {
            float hv = hr[f];
            s1 += hv * sa[f];
            s2 += hv * da[f];
        }
        es[rg * cHEADS + hd] = s1;
        ed[rg * cHEADS + hd] = s2;
    }

    // coalesced bf16 writeout
    size_t base = (size_t)blockIdx.x * 64 * cHID;
    #pragma unroll
    for (int it = 0; it < 8; it++) {
        int g   = tid + it * 256;
        int row = g >> 5;
        int c4  = (g & 31) * 4;
        float4 v = *(const float4*)&hl[row][c4];
        unsigned int p0 = pack2(v.x, v.y), p1 = pack2(v.z, v.w);
        *(uint2*)(hb + base + (size_t)row * cHID + c4) = make_uint2(p0, p1);
    }
}

// ---------------- t-plane agg: XCD-affine plane swizzle, identity node order ----------------
// 1D grid of (cN/16)*cT blocks: t = b & 7 (same t -> same XCD under round-robin dispatch),
// nodes block-contiguous (coalesced writes, contiguous ed reads).
// 16 lanes per row, 16B (8 bf16) per lane.
__global__ void agg_kernel(const unsigned short* __restrict__ hb, const float* __restrict__ es,
                           const float* __restrict__ ed,
                           const int* __restrict__ offs, const int* __restrict__ csr,
                           const float* __restrict__ bias, unsigned short* __restrict__ outb) {
    int b    = blockIdx.x;
    int t    = b & 7;
    int g    = b >> 3;
    int lrow = threadIdx.x >> 4;
    int n    = g * 16 + lrow;
    int j    = threadIdx.x & 15;        // features 8j..8j+7
    int head = j >> 2;
    size_t plane = (size_t)t * cN;
    int rho = t * cN + n;
    int s0 = offs[n], s1 = offs[n + 1];
    float edn = ed[(size_t)rho * cHEADS + head];
    const unsigned short* hp = hb + plane * cHID;
    const float* ep = es + plane * cHEADS;

    float acc[8] = {};
    float den = 0.f;
    int i = s0;
    for (; i + 1 < s1; i += 2) {
        int sa = csr[i], sb = csr[i + 1];
        uint4 ra = *(const uint4*)(hp + (size_t)sa * cHID + 8 * j);
        uint4 rb = *(const uint4*)(hp + (size_t)sb * cHID + 8 * j);
        float ea = ep[sa * cHEADS + head] + edn;
        float eb = ep[sb * cHEADS + head] + edn;
        ea = (ea >= 0.f) ? ea : cLEAKY * ea;
        eb = (eb >= 0.f) ? eb : cLEAKY * eb;
        float wa = __expf(ea), wb = __expf(eb);
        den += wa + wb;
        float l0, h0, l1, h1;
        unpack2(ra.x, l0, h0); acc[0] += wa * l0; acc[1] += wa * h0;
        unpack2(ra.y, l1, h1); acc[2] += wa * l1; acc[3] += wa * h1;
        unpack2(ra.z, l0, h0); acc[4] += wa * l0; acc[5] += wa * h0;
        unpack2(ra.w, l1, h1); acc[6] += wa * l1; acc[7] += wa * h1;
        unpack2(rb.x, l0, h0); acc[0] += wb * l0; acc[1] += wb * h0;
        unpack2(rb.y, l1, h1); acc[2] += wb * l1; acc[3] += wb * h1;
        unpack2(rb.z, l0, h0); acc[4] += wb * l0; acc[5] += wb * h0;
        unpack2(rb.w, l1, h1); acc[6] += wb * l1; acc[7] += wb * h1;
    }
    if (i < s1) {
        int sa = csr[i];
        uint4 ra = *(const uint4*)(hp + (size_t)sa * cHID + 8 * j);
        float ea = ep[sa * cHEADS + head] + edn;
        ea = (ea >= 0.f) ? ea : cLEAKY * ea;
        float wa = __expf(ea);
        den += wa;
        float l0, h0;
        unpack2(ra.x, l0, h0); acc[0] += wa * l0; acc[1] += wa * h0;
        unpack2(ra.y, l0, h0); acc[2] += wa * l0; acc[3] += wa * h0;
        unpack2(ra.z, l0, h0); acc[4] += wa * l0; acc[5] += wa * h0;
        unpack2(ra.w, l0, h0); acc[6] += wa * l0; acc[7] += wa * h0;
    }
    float inv = 1.f / (den + 1e-16f);
    float4 b0 = *(const float4*)(bias + 8 * j);
    float4 b1 = *(const float4*)(bias + 8 * j + 4);
    float r0 = acc[0] * inv + b0.x; r0 = (r0 > 0.f) ? r0 : expm1f(r0);
    float r1 = acc[1] * inv + b0.y; r1 = (r1 > 0.f) ? r1 : expm1f(r1);
    float r2 = acc[2] * inv + b0.z; r2 = (r2 > 0.f) ? r2 : expm1f(r2);
    float r3 = acc[3] * inv + b0.w; r3 = (r3 > 0.f) ? r3 : expm1f(r3);
    float r4 = acc[4] * inv + b1.x; r4 = (r4 > 0.f) ? r4 : expm1f(r4);
    float r5 = acc[5] * inv + b1.y; r5 = (r5 > 0.f) ? r5 : expm1f(r5);
    float r6 = acc[6] * inv + b1.z; r6 = (r6 > 0.f) ? r6 : expm1f(r6);
    float r7 = acc[7] * inv + b1.w; r7 = (r7 > 0.f) ? r7 : expm1f(r7);
    uint4 o;
    o.x = pack2(r0, r1); o.y = pack2(r2, r3); o.z = pack2(r4, r5); o.w = pack2(r6, r7);
    *(uint4*)(outb + (size_t)rho * cHID + 8 * j) = o;
}

// ---------------- MFMA MLP head: relu(X@lw1.T+lb1)@lw2.T + lb2 -> out[rho] ----------------
__global__ __launch_bounds__(256) void TemporalGAT_20005957665499_kernel(
        const unsigned short* __restrict__ X, const unsigned short* __restrict__ lw1b,
        const float* __restrict__ lb1, const float* __restrict__ lw2,
        const float* __restrict__ lb2, float* __restrict__ out) {
    int tid  = threadIdx.x;
    int wave = tid >> 6;
    int lane = tid & 63;
    int q    = lane >> 4;
    int mi   = lane & 15;
    int m0   = blockIdx.x * 64 + wave * 16;

    bf16x8 afrag[4];
    #pragma unroll
    for (int s = 0; s < 4; s++)
        afrag[s] = *(const bf16x8*)(X + (size_t)(m0 + mi) * cHID + s * 32 + q * 8);

    f32x4 acc[2];
    acc[0] = (f32x4){0.f, 0.f, 0.f, 0.f};
    acc[1] = (f32x4){0.f, 0.f, 0.f, 0.f};
    #pragma unroll
    for (int ct = 0; ct < 2; ct++) {
        int c = ct * 16 + mi;
        #pragma unroll
        for (int s = 0; s < 4; s++) {
            bf16x8 bfrag = *(const bf16x8*)(lw1b + (size_t)c * cHID + s * 32 + q * 8);
            acc[ct] = __builtin_amdgcn_mfma_f32_16x16x32_bf16(afrag[s], bfrag, acc[ct], 0, 0, 0);
        }
    }

    float lb1a = lb1[mi], lb1b_ = lb1[16 + mi];
    float lw2a = lw2[mi], lw2b_ = lw2[16 + mi];
    float l2 = lb2[0];
    #pragma unroll
    for (int r = 0; r < 4; r++) {
        float va = acc[0][r] + lb1a; va = fmaxf(va, 0.f);
        float vb = acc[1][r] + lb1b_; vb = fmaxf(vb, 0.f);
        float v = va * lw2a + vb * lw2b_;
        v += __shfl_xor(v, 1);
        v += __shfl_xor(v, 2);
        v += __shfl_xor(v, 4);
        v += __shfl_xor(v, 8);
        if (mi == 0) out[m0 + q * 4 + r] = v + l2;   // rho-major == [T,N] output layout
    }
}

// ---------------- launch ----------------
extern "C" void kernel_launch(void* const* d_in, const int* in_sizes, int n_in,
                              void* d_out, int out_size, void* d_ws, size_t ws_size,
                              hipStream_t stream) {
    const float* x   = (const float*)d_in[0];   // [N,T,64] fp32
    const int*   ei  = (const int*)d_in[1];
    const float* W1  = (const float*)d_in[2];
    const float* as1 = (const float*)d_in[3];
    const float* ad1 = (const float*)d_in[4];
    const float* b1  = (const float*)d_in[5];
    const float* W2  = (const float*)d_in[6];
    const float* as2 = (const float*)d_in[7];
    const float* ad2 = (const float*)d_in[8];
    const float* b2  = (const float*)d_in[9];
    const float* lw1 = (const float*)d_in[10];
    const float* lb1 = (const float*)d_in[11];
    const float* lw2 = (const float*)d_in[12];
    const float* lb2 = (const float*)d_in[13];
    float* out = (float*)d_out;                 // [T,N,1] fp32 == rho-major
    (void)in_sizes; (void)n_in; (void)out_size; (void)ws_size;

    // workspace carve (~150 MB of 256 MB), 256B-aligned
    char* ws = (char*)d_ws;
    size_t o = 0;
    auto carveN = [&](size_t bytes) { void* p = ws + o; o += (bytes + 255) & ~(size_t)255; return p; };
    unsigned short* xb   = (unsigned short*)carveN((size_t)cR * cFIN * 2);    // 20.5 MB
    unsigned short* hb   = (unsigned short*)carveN((size_t)cR * cHID * 2);    // 41 MB
    unsigned short* xb2  = (unsigned short*)carveN((size_t)cR * cHID * 2);    // 41 MB
    unsigned short* xb3  = (unsigned short*)carveN((size_t)cR * cHID * 2);    // 41 MB
    unsigned short* W1b  = (unsigned short*)carveN((size_t)cHID * cFIN * 2);
    unsigned short* W2b  = (unsigned short*)carveN((size_t)cHID * cHID * 2);
    unsigned short* lw1b = (unsigned short*)carveN((size_t)cF * cHID * 2);
    float* es_buf  = (float*)carveN((size_t)cR * cHEADS * 4);                 // 2.6 MB
    float* ed_buf  = (float*)carveN((size_t)cR * cHEADS * 4);
    int*   deg     = (int*)carveN((size_t)cN * 4);
    int*   offs    = (int*)carveN((size_t)(cN + 1) * 4);
    int*   cursor  = (int*)carveN((size_t)cN * 4);
    int*   csr     = (int*)carveN((size_t)cET * 4);

    // ---- conversions ----
    cvt_x_kernel<<<dim3(cN * cFIN / 256, cT), 256, 0, stream>>>(x, xb);
    cvt_w_kernel<<<(cHID * cFIN + cHID * cHID + cF * cHID + 255) / 256, 256, 0, stream>>>(
        W1, W2, lw1, W1b, W2b, lw1b);

    // ---- CSR build ----
    deg_init_kernel<<<(cN + 255) / 256, 256, 0, stream>>>(deg);
    deg_count_kernel<<<(cE + 255) / 256, 256, 0, stream>>>(ei, deg);
    scan_kernel<<<1, 256, 0, stream>>>(deg, offs, cursor);
    scatter_kernel<<<(cET + 255) / 256, 256, 0, stream>>>(ei, cursor, csr);

    // ---- layer 1 ----
    gemm_mfma_kernel<cFIN><<<cR / 64, 256, 0, stream>>>(xb, W1b, as1, ad1, hb, es_buf, ed_buf);
    agg_kernel<<<(cN / 16) * cT, 256, 0, stream>>>(hb, es_buf, ed_buf, offs, csr, b1, xb2);
    // ---- layer 2 ----
    gemm_mfma_kernel<cHID><<<cR / 64, 256, 0, stream>>>(xb2, W2b, as2, ad2, hb, es_buf, ed_buf);
    agg_kernel<<<(cN / 16) * cT, 256, 0, stream>>>(hb, es_buf, ed_buf, offs, csr, b2, xb3);
    // ---- MFMA MLP head -> out ----
    TemporalGAT_20005957665499_kernel<<<cR / 64, 256, 0, stream>>>(xb3, lw1b, lb1, lw2, lb2, out);
}

// Round 15
// 417.641 us; speedup vs baseline: 1.3217x; 1.0641x over previous
//
#include <hip/hip_runtime.h>

// ---------------- problem constants ----------------
constexpr int cN     = 20000;
constexpr int cT     = 8;
constexpr int cFIN   = 64;
constexpr int cHEADS = 4;
constexpr int cF     = 32;
constexpr int cHID   = 128;        // cHEADS * cF
constexpr int cE     = 320000;
constexpr int cET    = cE + cN;    // edges + self loops
constexpr int cR     = cN * cT;    // 160000 batched rows, rho = t*N + n (t-major)
constexpr float cLEAKY = 0.2f;

typedef __attribute__((ext_vector_type(8))) short bf16x8;   // MFMA A/B frag
typedef __attribute__((ext_vector_type(4))) float f32x4;    // MFMA C/D frag

static __device__ __forceinline__ unsigned short f2bfu(float f) {
    unsigned int u;
    __builtin_memcpy(&u, &f, 4);
    u += 0x7FFFu + ((u >> 16) & 1u);
    return (unsigned short)(u >> 16);
}
static __device__ __forceinline__ void unpack2(unsigned int v, float& lo, float& hi) {
    unsigned int ul = v << 16, uh = v & 0xFFFF0000u;
    __builtin_memcpy(&lo, &ul, 4);
    __builtin_memcpy(&hi, &uh, 4);
}
static __device__ __forceinline__ unsigned int pack2(float lo, float hi) {
    unsigned int ul, uh;
    __builtin_memcpy(&ul, &lo, 4);
    __builtin_memcpy(&uh, &hi, 4);
    ul += 0x7FFFu + ((ul >> 16) & 1u);
    uh += 0x7FFFu + ((uh >> 16) & 1u);
    return (ul >> 16) | (uh & 0xFFFF0000u);
}

// ---------------- weight conversion ----------------
__global__ void cvt_w_kernel(const float* W1, const float* W2, const float* lw1,
                             unsigned short* W1b, unsigned short* W2b, unsigned short* lw1b) {
    int i = blockIdx.x * 256 + threadIdx.x;
    if (i < cHID * cFIN)                      W1b[i] = f2bfu(W1[i]);
    else if (i < cHID * cFIN + cHID * cHID)   W2b[i - cHID * cFIN] = f2bfu(W2[i - cHID * cFIN]);
    else if (i < cHID * cFIN + cHID * cHID + cF * cHID)
        lw1b[i - cHID * cFIN - cHID * cHID] = f2bfu(lw1[i - cHID * cFIN - cHID * cHID]);
}

// ---------------- CSR build ----------------
__global__ void deg_init_kernel(int* deg) {
    int n = blockIdx.x * blockDim.x + threadIdx.x;
    if (n < cN) deg[n] = 1;   // self loop
}
__global__ void deg_count_kernel(const int* ei, int* deg) {
    int e = blockIdx.x * blockDim.x + threadIdx.x;
    if (e < cE) atomicAdd(&deg[ei[cE + e]], 1);
}
__global__ void scan_kernel(const int* deg, int* offs, int* cur) {
    __shared__ int lds[256];
    const int CH = 80;
    int tid  = threadIdx.x;
    int base = tid * CH;
    int tot = 0;
    for (int j = 0; j < CH; j++) {
        int idx = base + j;
        if (idx < cN) tot += deg[idx];
    }
    lds[tid] = tot;
    __syncthreads();
    for (int off = 1; off < 256; off <<= 1) {
        int v = (tid >= off) ? lds[tid - off] : 0;
        __syncthreads();
        lds[tid] += v;
        __syncthreads();
    }
    int run = lds[tid] - tot;
    for (int j = 0; j < CH; j++) {
        int idx = base + j;
        if (idx < cN) { offs[idx] = run; cur[idx] = run; run += deg[idx]; }
    }
    if (tid == 255) offs[cN] = lds[255];
}
__global__ void scatter_kernel(const int* ei, int* cur, int* csr) {
    int e = blockIdx.x * blockDim.x + threadIdx.x;
    if (e >= cET) return;
    int s, d;
    if (e < cE) { s = ei[e]; d = ei[cE + e]; }
    else        { s = e - cE; d = s; }
    int pos = atomicAdd(&cur[d], 1);
    csr[pos] = s;
}

// ---------------- GEMM1 (fused fp32->bf16 cvt of x) + scores ----------------
// rows rho = t*cN+n; reads x [N,T,64] fp32 directly, converts in-register (same RNE).
__global__ __launch_bounds__(256) void gemm1_fused_kernel(
        const float* __restrict__ x, const unsigned short* __restrict__ W,
        const float* __restrict__ a_src, const float* __restrict__ a_dst,
        unsigned short* __restrict__ hb, float* __restrict__ es, float* __restrict__ ed) {
    __shared__ float hl[64][132];
    int tid  = threadIdx.x;
    int wave = tid >> 6;
    int lane = tid & 63;
    int q    = lane >> 4;
    int mi   = lane & 15;
    int m0   = blockIdx.x * 64 + wave * 16;

    int rho = m0 + mi;
    int t = rho / cN;                 // magic-mul div (constant divisor)
    int n = rho - t * cN;
    const float* xr = x + (size_t)n * (cT * cFIN) + t * cFIN;

    bf16x8 afrag[2];
    #pragma unroll
    for (int s = 0; s < 2; s++) {
        float4 v0 = *(const float4*)(xr + s * 32 + q * 8);
        float4 v1 = *(const float4*)(xr + s * 32 + q * 8 + 4);
        bf16x8 f;
        f[0] = (short)f2bfu(v0.x); f[1] = (short)f2bfu(v0.y);
        f[2] = (short)f2bfu(v0.z); f[3] = (short)f2bfu(v0.w);
        f[4] = (short)f2bfu(v1.x); f[5] = (short)f2bfu(v1.y);
        f[6] = (short)f2bfu(v1.z); f[7] = (short)f2bfu(v1.w);
        afrag[s] = f;
    }

    f32x4 acc[8];
    #pragma unroll
    for (int ct = 0; ct < 8; ct++) acc[ct] = (f32x4){0.f, 0.f, 0.f, 0.f};
    #pragma unroll
    for (int ct = 0; ct < 8; ct++) {
        int c = ct * 16 + mi;
        #pragma unroll
        for (int s = 0; s < 2; s++) {
            bf16x8 bfrag = *(const bf16x8*)(W + (size_t)c * cFIN + s * 32 + q * 8);
            acc[ct] = __builtin_amdgcn_mfma_f32_16x16x32_bf16(afrag[s], bfrag, acc[ct], 0, 0, 0);
        }
    }

    #pragma unroll
    for (int ct = 0; ct < 8; ct++)
        #pragma unroll
        for (int r = 0; r < 4; r++)
            hl[wave * 16 + q * 4 + r][ct * 16 + mi] = acc[ct][r];
    __syncthreads();

    {
        int r2 = tid & 63;
        int hd = tid >> 6;
        int rg = blockIdx.x * 64 + r2;
        const float* hr = &hl[r2][hd * cF];
        const float* sa = a_src + hd * cF;
        const float* da = a_dst + hd * cF;
        float s1 = 0.f, s2 = 0.f;
        #pragma unroll 8
        for (int f = 0; f < cF; f++) {
            float hv = hr[f];
            s1 += hv * sa[f];
            s2 += hv * da[f];
        }
        es[rg * cHEADS + hd] = s1;
        ed[rg * cHEADS + hd] = s2;
    }

    size_t base = (size_t)blockIdx.x * 64 * cHID;
    #pragma unroll
    for (int it = 0; it < 8; it++) {
        int g   = tid + it * 256;
        int row = g >> 5;
        int c4  = (g & 31) * 4;
        float4 v = *(const float4*)&hl[row][c4];
        unsigned int p0 = pack2(v.x, v.y), p1 = pack2(v.z, v.w);
        *(uint2*)(hb + base + (size_t)row * cHID + c4) = make_uint2(p0, p1);
    }
}

// ---------------- GEMM2 (bf16 A) + scores, K=128 ----------------
__global__ __launch_bounds__(256) void gemm2_mfma_kernel(
        const unsigned short* __restrict__ A, const unsigned short* __restrict__ W,
        const float* __restrict__ a_src, const float* __restrict__ a_dst,
        unsigned short* __restrict__ hb, float* __restrict__ es, float* __restrict__ ed) {
    __shared__ float hl[64][132];
    int tid  = threadIdx.x;
    int wave = tid >> 6;
    int lane = tid & 63;
    int q    = lane >> 4;
    int mi   = lane & 15;
    int m0   = blockIdx.x * 64 + wave * 16;

    bf16x8 afrag[4];
    #pragma unroll
    for (int s = 0; s < 4; s++)
        afrag[s] = *(const bf16x8*)(A + (size_t)(m0 + mi) * cHID + s * 32 + q * 8);

    f32x4 acc[8];
    #pragma unroll
    for (int ct = 0; ct < 8; ct++) acc[ct] = (f32x4){0.f, 0.f, 0.f, 0.f};
    #pragma unroll
    for (int ct = 0; ct < 8; ct++) {
        int c = ct * 16 + mi;
        #pragma unroll
        for (int s = 0; s < 4; s++) {
            bf16x8 bfrag = *(const bf16x8*)(W + (size_t)c * cHID + s * 32 + q * 8);
            acc[ct] = __builtin_amdgcn_mfma_f32_16x16x32_bf16(afrag[s], bfrag, acc[ct], 0, 0, 0);
        }
    }

    #pragma unroll
    for (int ct = 0; ct < 8; ct++)
        #pragma unroll
        for (int r = 0; r < 4; r++)
            hl[wave * 16 + q * 4 + r][ct * 16 + mi] = acc[ct][r];
    __syncthreads();

    {
        int r2 = tid & 63;
        int hd = tid >> 6;
        int rg = blockIdx.x * 64 + r2;
        const float* hr = &hl[r2][hd * cF];
        const float* sa = a_src + hd * cF;
        const float* da = a_dst + hd * cF;
        float s1 = 0.f, s2 = 0.f;
        #pragma unroll 8
        for (int f = 0; f < cF; f++) {
            float hv = hr[f];
            s1 += hv * sa[f];
            s2 += hv * da[f];
        }
        es[rg * cHEADS + hd] = s1;
        ed[rg * cHEADS + hd] = s2;
    }

    size_t base = (size_t)blockIdx.x * 64 * cHID;
    #pragma unroll
    for (int it = 0; it < 8; it++) {
        int g   = tid + it * 256;
        int row = g >> 5;
        int c4  = (g & 31) * 4;
        float4 v = *(const float4*)&hl[row][c4];
        unsigned int p0 = pack2(v.x, v.y), p1 = pack2(v.z, v.w);
        *(uint2*)(hb + base + (size_t)row * cHID + c4) = make_uint2(p0, p1);
    }
}

// ---------------- t-plane agg: XCD swizzle, 32-bit offsets, unroll-4 ----------------
// 1D grid (cN/16)*cT: t = b & 7; nodes block-contiguous. 16 lanes/row, 16B per lane.
__global__ __launch_bounds__(256) void agg_kernel(
        const unsigned short* __restrict__ hb, const float* __restrict__ es,
        const float* __restrict__ ed,
        const int* __restrict__ offs, const int* __restrict__ csr,
        const float* __restrict__ bias, unsigned short* __restrict__ outb) {
    int b    = blockIdx.x;
    int t    = b & 7;
    int g    = b >> 3;
    int lrow = threadIdx.x >> 4;
    int n    = g * 16 + lrow;
    int j    = threadIdx.x & 15;        // features 8j..8j+7
    int head = j >> 2;
    int rho  = t * cN + n;
    int s0 = offs[n], s1 = offs[n + 1];
    float edn = ed[(size_t)rho * cHEADS + head];
    const char* hpc = (const char*)(hb + (size_t)t * cN * cHID);     // plane base
    const char* epc = (const char*)(es + (size_t)t * cN * cHEADS);
    const char* cc  = (const char*)csr;
    unsigned jo = (unsigned)j * 16u;
    unsigned ho = (unsigned)head * 4u;

    float acc[8] = {};
    float den = 0.f;
    int i = s0;
    for (; i + 3 < s1; i += 4) {
        unsigned io = (unsigned)i * 4u;
        int sa = *(const int*)(cc + io);
        int sb = *(const int*)(cc + io + 4u);
        int sc = *(const int*)(cc + io + 8u);
        int sd = *(const int*)(cc + io + 12u);
        uint4 ra = *(const uint4*)(hpc + (((unsigned)sa) << 8) + jo);
        uint4 rb = *(const uint4*)(hpc + (((unsigned)sb) << 8) + jo);
        uint4 rc = *(const uint4*)(hpc + (((unsigned)sc) << 8) + jo);
        uint4 rd = *(const uint4*)(hpc + (((unsigned)sd) << 8) + jo);
        float ea = *(const float*)(epc + (((unsigned)sa) << 4) + ho) + edn;
        float eb = *(const float*)(epc + (((unsigned)sb) << 4) + ho) + edn;
        float ec = *(const float*)(epc + (((unsigned)sc) << 4) + ho) + edn;
        float ee = *(const float*)(epc + (((unsigned)sd) << 4) + ho) + edn;
        ea = (ea >= 0.f) ? ea : cLEAKY * ea;
        eb = (eb >= 0.f) ? eb : cLEAKY * eb;
        ec = (ec >= 0.f) ? ec : cLEAKY * ec;
        ee = (ee >= 0.f) ? ee : cLEAKY * ee;
        float wa = __expf(ea), wb = __expf(eb), wc = __expf(ec), wd = __expf(ee);
        den += wa; den += wb; den += wc; den += wd;
        float lo, hi;
        unpack2(ra.x, lo, hi); acc[0] += wa * lo; acc[1] += wa * hi;
        unpack2(ra.y, lo, hi); acc[2] += wa * lo; acc[3] += wa * hi;
        unpack2(ra.z, lo, hi); acc[4] += wa * lo; acc[5] += wa * hi;
        unpack2(ra.w, lo, hi); acc[6] += wa * lo; acc[7] += wa * hi;
        unpack2(rb.x, lo, hi); acc[0] += wb * lo; acc[1] += wb * hi;
        unpack2(rb.y, lo, hi); acc[2] += wb * lo; acc[3] += wb * hi;
        unpack2(rb.z, lo, hi); acc[4] += wb * lo; acc[5] += wb * hi;
        unpack2(rb.w, lo, hi); acc[6] += wb * lo; acc[7] += wb * hi;
        unpack2(rc.x, lo, hi); acc[0] += wc * lo; acc[1] += wc * hi;
        unpack2(rc.y, lo, hi); acc[2] += wc * lo; acc[3] += wc * hi;
        unpack2(rc.z, lo, hi); acc[4] += wc * lo; acc[5] += wc * hi;
        unpack2(rc.w, lo, hi); acc[6] += wc * lo; acc[7] += wc * hi;
        unpack2(rd.x, lo, hi); acc[0] += wd * lo; acc[1] += wd * hi;
        unpack2(rd.y, lo, hi); acc[2] += wd * lo; acc[3] += wd * hi;
        unpack2(rd.z, lo, hi); acc[4] += wd * lo; acc[5] += wd * hi;
        unpack2(rd.w, lo, hi); acc[6] += wd * lo; acc[7] += wd * hi;
    }
    for (; i < s1; i++) {
        int sa = *(const int*)(cc + (unsigned)i * 4u);
        uint4 ra = *(const uint4*)(hpc + (((unsigned)sa) << 8) + jo);
        float ea = *(const float*)(epc + (((unsigned)sa) << 4) + ho) + edn;
        ea = (ea >= 0.f) ? ea : cLEAKY * ea;
        float wa = __expf(ea);
        den += wa;
        float lo, hi;
        unpack2(ra.x, lo, hi); acc[0] += wa * lo; acc[1] += wa * hi;
        unpack2(ra.y, lo, hi); acc[2] += wa * lo; acc[3] += wa * hi;
        unpack2(ra.z, lo, hi); acc[4] += wa * lo; acc[5] += wa * hi;
        unpack2(ra.w, lo, hi); acc[6] += wa * lo; acc[7] += wa * hi;
    }
    float inv = 1.f / (den + 1e-16f);
    float4 b0 = *(const float4*)(bias + 8 * j);
    float4 b1 = *(const float4*)(bias + 8 * j + 4);
    float r0 = acc[0] * inv + b0.x; r0 = (r0 > 0.f) ? r0 : expm1f(r0);
    float r1 = acc[1] * inv + b0.y; r1 = (r1 > 0.f) ? r1 : expm1f(r1);
    float r2 = acc[2] * inv + b0.z; r2 = (r2 > 0.f) ? r2 : expm1f(r2);
    float r3 = acc[3] * inv + b0.w; r3 = (r3 > 0.f) ? r3 : expm1f(r3);
    float r4 = acc[4] * inv + b1.x; r4 = (r4 > 0.f) ? r4 : expm1f(r4);
    float r5 = acc[5] * inv + b1.y; r5 = (r5 > 0.f) ? r5 : expm1f(r5);
    float r6 = acc[6] * inv + b1.z; r6 = (r6 > 0.f) ? r6 : expm1f(r6);
    float r7 = acc[7] * inv + b1.w; r7 = (r7 > 0.f) ? r7 : expm1f(r7);
    uint4 o;
    o.x = pack2(r0, r1); o.y = pack2(r2, r3); o.z = pack2(r4, r5); o.w = pack2(r6, r7);
    *(uint4*)(outb + (size_t)rho * cHID + 8 * j) = o;
}

// ---------------- MFMA MLP head: relu(X@lw1.T+lb1)@lw2.T + lb2 -> out[rho] ----------------
__global__ __launch_bounds__(256) void TemporalGAT_20005957665499_kernel(
        const unsigned short* __restrict__ X, const unsigned short* __restrict__ lw1b,
        const float* __restrict__ lb1, const float* __restrict__ lw2,
        const float* __restrict__ lb2, float* __restrict__ out) {
    int tid  = threadIdx.x;
    int wave = tid >> 6;
    int lane = tid & 63;
    int q    = lane >> 4;
    int mi   = lane & 15;
    int m0   = blockIdx.x * 64 + wave * 16;

    bf16x8 afrag[4];
    #pragma unroll
    for (int s = 0; s < 4; s++)
        afrag[s] = *(const bf16x8*)(X + (size_t)(m0 + mi) * cHID + s * 32 + q * 8);

    f32x4 acc[2];
    acc[0] = (f32x4){0.f, 0.f, 0.f, 0.f};
    acc[1] = (f32x4){0.f, 0.f, 0.f, 0.f};
    #pragma unroll
    for (int ct = 0; ct < 2; ct++) {
        int c = ct * 16 + mi;
        #pragma unroll
        for (int s = 0; s < 4; s++) {
            bf16x8 bfrag = *(const bf16x8*)(lw1b + (size_t)c * cHID + s * 32 + q * 8);
            acc[ct] = __builtin_amdgcn_mfma_f32_16x16x32_bf16(afrag[s], bfrag, acc[ct], 0, 0, 0);
        }
    }

    float lb1a = lb1[mi], lb1b_ = lb1[16 + mi];
    float lw2a = lw2[mi], lw2b_ = lw2[16 + mi];
    float l2 = lb2[0];
    #pragma unroll
    for (int r = 0; r < 4; r++) {
        float va = acc[0][r] + lb1a; va = fmaxf(va, 0.f);
        float vb = acc[1][r] + lb1b_; vb = fmaxf(vb, 0.f);
        float v = va * lw2a + vb * lw2b_;
        v += __shfl_xor(v, 1);
        v += __shfl_xor(v, 2);
        v += __shfl_xor(v, 4);
        v += __shfl_xor(v, 8);
        if (mi == 0) out[m0 + q * 4 + r] = v + l2;   // rho-major == [T,N] output layout
    }
}

// ---------------- launch ----------------
extern "C" void kernel_launch(void* const* d_in, const int* in_sizes, int n_in,
                              void* d_out, int out_size, void* d_ws, size_t ws_size,
                              hipStream_t stream) {
    const float* x   = (const float*)d_in[0];   // [N,T,64] fp32
    const int*   ei  = (const int*)d_in[1];
    const float* W1  = (const float*)d_in[2];
    const float* as1 = (const float*)d_in[3];
    const float* ad1 = (const float*)d_in[4];
    const float* b1  = (const float*)d_in[5];
    const float* W2  = (const float*)d_in[6];
    const float* as2 = (const float*)d_in[7];
    const float* ad2 = (const float*)d_in[8];
    const float* b2  = (const float*)d_in[9];
    const float* lw1 = (const float*)d_in[10];
    const float* lb1 = (const float*)d_in[11];
    const float* lw2 = (const float*)d_in[12];
    const float* lb2 = (const float*)d_in[13];
    float* out = (float*)d_out;                 // [T,N,1] fp32 == rho-major
    (void)in_sizes; (void)n_in; (void)out_size; (void)ws_size;

    // workspace carve (~130 MB of 256 MB), 256B-aligned
    char* ws = (char*)d_ws;
    size_t o = 0;
    auto carveN = [&](size_t bytes) { void* p = ws + o; o += (bytes + 255) & ~(size_t)255; return p; };
    unsigned short* hb   = (unsigned short*)carveN((size_t)cR * cHID * 2);    // 41 MB
    unsigned short* xb2  = (unsigned short*)carveN((size_t)cR * cHID * 2);    // 41 MB
    unsigned short* xb3  = (unsigned short*)carveN((size_t)cR * cHID * 2);    // 41 MB
    unsigned short* W1b  = (unsigned short*)carveN((size_t)cHID * cFIN * 2);
    unsigned short* W2b  = (unsigned short*)carveN((size_t)cHID * cHID * 2);
    unsigned short* lw1b = (unsigned short*)carveN((size_t)cF * cHID * 2);
    float* es_buf  = (float*)carveN((size_t)cR * cHEADS * 4);                 // 2.6 MB
    float* ed_buf  = (float*)carveN((size_t)cR * cHEADS * 4);
    int*   deg     = (int*)carveN((size_t)cN * 4);
    int*   offs    = (int*)carveN((size_t)(cN + 1) * 4);
    int*   cursor  = (int*)carveN((size_t)cN * 4);
    int*   csr     = (int*)carveN((size_t)cET * 4);

    // ---- weight conversion ----
    cvt_w_kernel<<<(cHID * cFIN + cHID * cHID + cF * cHID + 255) / 256, 256, 0, stream>>>(
        W1, W2, lw1, W1b, W2b, lw1b);

    // ---- CSR build ----
    deg_init_kernel<<<(cN + 255) / 256, 256, 0, stream>>>(deg);
    deg_count_kernel<<<(cE + 255) / 256, 256, 0, stream>>>(ei, deg);
    scan_kernel<<<1, 256, 0, stream>>>(deg, offs, cursor);
    scatter_kernel<<<(cET + 255) / 256, 256, 0, stream>>>(ei, cursor, csr);

    // ---- layer 1 (x read + cvt fused into GEMM) ----
    gemm1_fused_kernel<<<cR / 64, 256, 0, stream>>>(x, W1b, as1, ad1, hb, es_buf, ed_buf);
    agg_kernel<<<(cN / 16) * cT, 256, 0, stream>>>(hb, es_buf, ed_buf, offs, csr, b1, xb2);
    // ---- layer 2 ----
    gemm2_mfma_kernel<<<cR / 64, 256, 0, stream>>>(xb2, W2b, as2, ad2, hb, es_buf, ed_buf);
    agg_kernel<<<(cN / 16) * cT, 256, 0, stream>>>(hb, es_buf, ed_buf, offs, csr, b2, xb3);
    // ---- MFMA MLP head -> out ----
    TemporalGAT_20005957665499_kernel<<<cR / 64, 256, 0, stream>>>(xb3, lw1b, lb1, lw2, lb2, out);
}